// Round 9
// baseline (313.020 us; speedup 1.0000x reference)
//
#include <hip/hip_runtime.h>
#include <math.h>

// B=8, N=1024, DIM=768, H=12, dh=64 -> M=8192, EQKV=2304
// Split-precision bf16: x ~= hi + lo. 3-term MFMA GEMMs, 3-term QK, 2-term PV.
// gemm1 (qkv) = 8-phase-style pipelined kernel (k_gemm8): BM128xBN192, BK32,
// 6 waves, dbuf LDS, stage-overlap + per-phase barriers + setprio. All cross-
// wave hazards fenced by __syncthreads (correctness-safe; no asm waitcnt).

typedef __attribute__((ext_vector_type(8))) short short8;
typedef __attribute__((ext_vector_type(4))) float f32x4;

#define MFMA(a, b, c) __builtin_amdgcn_mfma_f32_16x16x32_bf16((a), (b), (c), 0, 0, 0)

#define GLDS16(gp, lp) \
  __builtin_amdgcn_global_load_lds((__attribute__((address_space(1))) const void*)(gp), \
                                   (__attribute__((address_space(3))) void*)(lp), 16, 0, 0)

__device__ __forceinline__ unsigned short f2bf(float x) {
  unsigned u = __builtin_bit_cast(unsigned, x);
  return (unsigned short)((u + 0x7FFFu + ((u >> 16) & 1u)) >> 16);
}
__device__ __forceinline__ float bf2f(unsigned short h) {
  unsigned u = ((unsigned)h) << 16;
  return __builtin_bit_cast(float, u);
}

// ---------------------------------------------------------------------------
// fp32 -> planar (hi, lo) bf16 split, 8 elem/thread.
// ---------------------------------------------------------------------------
__global__ __launch_bounds__(256)
void k_split(const float* __restrict__ x, short* __restrict__ h,
             short* __restrict__ l, int n8)
{
  const int i = blockIdx.x * 256 + threadIdx.x;
  if (i >= n8) return;
  float4 a = ((const float4*)x)[2 * i];
  float4 b = ((const float4*)x)[2 * i + 1];
  float v[8] = {a.x, a.y, a.z, a.w, b.x, b.y, b.z, b.w};
  short8 hh, ll;
#pragma unroll
  for (int e = 0; e < 8; ++e) {
    unsigned short hi = f2bf(v[e]);
    hh[e] = (short)hi;
    ll[e] = (short)f2bf(v[e] - bf2f(hi));
  }
  ((short8*)h)[i] = hh;
  ((short8*)l)[i] = ll;
}

// ---------------------------------------------------------------------------
// gemm1: qkv = img @ Wqkv^T, 3-term split, 8-phase-style pipeline.
// BM=128, BN=192, BK=32, K=768 fixed. 384 thr = 6 waves (2M x 3N),
// per-wave out 64x64. LDS 80 KiB dbuf -> 2 blocks/CU; grid 64x12=768 (3/CU).
// Species falls out per-wave: wn=0 -> q, wn=1 -> k, wn=2 -> v; head = by.
// ---------------------------------------------------------------------------
__global__ __launch_bounds__(384, 3)
void k_gemm8(const short* __restrict__ AH, const short* __restrict__ AL,
             const short* __restrict__ WH, const short* __restrict__ WL,
             short* __restrict__ qkH, short* __restrict__ qkL,
             short* __restrict__ vTH, short* __restrict__ vTL)
{
  __shared__ __align__(16) short As[2][128 * 64];   // 2 x 16 KiB
  __shared__ __align__(16) short Bs[2][192 * 64];   // 2 x 24 KiB

  const int tid = threadIdx.x, lane = tid & 63, w = tid >> 6;
  const int wm = w / 3, wn = w - wm * 3;            // 2M x 3N wave grid
  const int fr = lane & 15, g = lane >> 4;
  const int l3 = lane >> 3;
  const int ssrc = (lane & 7) ^ l3;                 // swizzled source slot
  const int bm = blockIdx.x * 128, bn = blockIdx.y * 192;
  const int by = blockIdx.y;                        // head 0..11

  const short* aplane = (ssrc < 4) ? AH : AL;
  const short* wplane = (ssrc < 4) ? WH : WL;
  const int scol = (ssrc & 3) * 8;
  const bool isA = (w < 2);

  const f32x4 zero4 = {0.f, 0.f, 0.f, 0.f};
  f32x4 acc[4][4];
#pragma unroll
  for (int i = 0; i < 4; ++i)
#pragma unroll
    for (int j = 0; j < 4; ++j) acc[i][j] = zero4;

  // stage one 1024B chunk (8 rows): A-waves chunk ca = w*8+c (16 total),
  // B-waves chunk cb = (w-2)*6+c (24 total).
  auto stage = [&](int buf, int kt, int c) {
    const int k0 = kt << 5;
    if (isA) {
      const int ca = w * 8 + c;
      GLDS16(aplane + (size_t)(bm + ca * 8 + l3) * 768 + k0 + scol, &As[buf][ca * 512]);
    } else {
      const int cb = (w - 2) * 6 + c;
      GLDS16(wplane + (size_t)(bn + cb * 8 + l3) * 768 + k0 + scol, &Bs[buf][cb * 512]);
    }
  };

  // prologue: stage tile 0 fully
#pragma unroll
  for (int c = 0; c < 8; ++c)
    if (c < (isA ? 8 : 6)) stage(0, 0, c);
  __syncthreads();

  for (int kt = 0; kt < 24; ++kt) {
    const int cur = kt & 1, nxt = cur ^ 1;
    const bool more = (kt < 23);

    // b-fragments for this tile (phase-0 reads)
    short8 bHf[4], bLf[4];
#pragma unroll
    for (int j = 0; j < 4; ++j) {
      const int rb = wn * 64 + j * 16 + fr;
      bHf[j] = *(const short8*)&Bs[cur][rb * 64 + ((g ^ (rb & 7)) * 8)];
      bLf[j] = *(const short8*)&Bs[cur][rb * 64 + (((4 + g) ^ (rb & 7)) * 8)];
    }

#pragma unroll
    for (int p = 0; p < 4; ++p) {
      const int ra = wm * 64 + p * 16 + fr;
      short8 aHf = *(const short8*)&As[cur][ra * 64 + ((g ^ (ra & 7)) * 8)];
      short8 aLf = *(const short8*)&As[cur][ra * 64 + (((4 + g) ^ (ra & 7)) * 8)];

      // stage next tile: A-waves 4+4 in phases 0/1, B-waves 3+3.
      if (more) {
        if (p == 0) {
          stage(nxt, kt + 1, 0); stage(nxt, kt + 1, 1); stage(nxt, kt + 1, 2);
          if (isA) stage(nxt, kt + 1, 3);
        } else if (p == 1) {
          if (isA) { stage(nxt, kt + 1, 4); stage(nxt, kt + 1, 5);
                     stage(nxt, kt + 1, 6); stage(nxt, kt + 1, 7); }
          else     { stage(nxt, kt + 1, 3); stage(nxt, kt + 1, 4);
                     stage(nxt, kt + 1, 5); }
        }
      }

      __builtin_amdgcn_s_barrier();
      __builtin_amdgcn_s_setprio(1);
#pragma unroll
      for (int j = 0; j < 4; ++j) {
        acc[p][j] = MFMA(aHf, bHf[j], acc[p][j]);
        acc[p][j] = MFMA(aHf, bLf[j], acc[p][j]);
        acc[p][j] = MFMA(aLf, bHf[j], acc[p][j]);
      }
      __builtin_amdgcn_s_setprio(0);
      if (p < 3) __builtin_amdgcn_s_barrier();
    }
    __syncthreads();   // tile boundary: drains vmcnt (stage of nxt) + lgkm
  }

  // ---- epilogue (D-layout: col=lane&15, row=(lane>>4)*4+r) ----
  // species = wn (0:q 1:k 2:v), head = by.
  if (wn < 2) {
#pragma unroll
    for (int i = 0; i < 4; ++i)
#pragma unroll
      for (int j = 0; j < 4; ++j) {
        const int row = bm + wm * 64 + i * 16 + g * 4;
        const int col = by * 128 + wn * 64 + j * 16 + fr;
        const size_t base = (size_t)row * 1536 + col;
#pragma unroll
        for (int r = 0; r < 4; ++r) {
          const float x = acc[i][j][r];
          const unsigned short hi = f2bf(x);
          qkH[base + (size_t)r * 1536] = (short)hi;
          qkL[base + (size_t)r * 1536] = (short)f2bf(x - bf2f(hi));
        }
      }
  } else {
#pragma unroll
    for (int i = 0; i < 4; ++i) {
      const int n0 = bm + wm * 64 + i * 16 + g * 4;
      const int b = n0 >> 10, n = n0 & 1023;
#pragma unroll
      for (int j = 0; j < 4; ++j) {
        const int dv = j * 16 + fr;
        short4 h4, l4;
#pragma unroll
        for (int r = 0; r < 4; ++r) {
          const float x = acc[i][j][r];
          const unsigned short hi = f2bf(x);
          ((short*)&h4)[r] = (short)hi;
          ((short*)&l4)[r] = (short)f2bf(x - bf2f(hi));
        }
        const size_t vidx = ((size_t)(b * 12 + by) * 64 + dv) * 1024 + n;
        *(short4*)&vTH[vidx] = h4;
        *(short4*)&vTL[vidx] = l4;
      }
    }
  }
}

// ---------------------------------------------------------------------------
// gemm2 (proven round-8 kernel): C = (AH+AL)*(WH+WL)^T + bias, fp32 out.
// 128x128 tile, BK=32, 256 thr, 2-phase, swizzled global_load_lds staging.
// ---------------------------------------------------------------------------
__global__ __launch_bounds__(256, 3)
void k_gemm(const short* __restrict__ AH, const short* __restrict__ AL,
            const short* __restrict__ WH, const short* __restrict__ WL,
            const float* __restrict__ bias, float* __restrict__ Cf,
            int Ndim, int K)
{
  __shared__ __align__(16) short As[128 * 64];
  __shared__ __align__(16) short Ws[128 * 64];

  const int tid = threadIdx.x, lane = tid & 63, w = tid >> 6;
  const int wm = w >> 1, wn = w & 1;
  const int fr = lane & 15, g = lane >> 4;
  const int bm = blockIdx.x * 128, bn = blockIdx.y * 128;

  const int l3 = lane >> 3;
  const int ssrc = (lane & 7) ^ l3;

  const f32x4 zero4 = {0.f, 0.f, 0.f, 0.f};
  f32x4 acc[4][4];
#pragma unroll
  for (int i = 0; i < 4; ++i)
#pragma unroll
    for (int j = 0; j < 4; ++j) acc[i][j] = zero4;

  const short* aplane = (ssrc < 4) ? AH : AL;
  const short* wplane = (ssrc < 4) ? WH : WL;
  const int scol = (ssrc & 3) * 8;

  const int nk = K >> 5;
  for (int kt = 0; kt < nk; ++kt) {
    const int k0 = kt << 5;
    __syncthreads();
#pragma unroll
    for (int c = 0; c < 8; ++c) {
      const int gidx = w * 8 + c;
      const int ch = gidx & 15;
      const int row = ch * 8 + l3;
      if (gidx < 16) {
        GLDS16(aplane + (size_t)(bm + row) * K + k0 + scol, &As[ch * 512]);
      } else {
        GLDS16(wplane + (size_t)(bn + row) * K + k0 + scol, &Ws[ch * 512]);
      }
    }
    __syncthreads();

    short8 aH[4], aL[4], bH[4], bL[4];
#pragma unroll
    for (int i = 0; i < 4; ++i) {
      const int ra = wm * 64 + i * 16 + fr;
      aH[i] = *(const short8*)&As[ra * 64 + ((g ^ (ra & 7)) * 8)];
      aL[i] = *(const short8*)&As[ra * 64 + (((4 + g) ^ (ra & 7)) * 8)];
      const int rb = wn * 64 + i * 16 + fr;
      bH[i] = *(const short8*)&Ws[rb * 64 + ((g ^ (rb & 7)) * 8)];
      bL[i] = *(const short8*)&Ws[rb * 64 + (((4 + g) ^ (rb & 7)) * 8)];
    }
#pragma unroll
    for (int i = 0; i < 4; ++i)
#pragma unroll
      for (int j = 0; j < 4; ++j) {
        acc[i][j] = MFMA(aH[i], bH[j], acc[i][j]);
        acc[i][j] = MFMA(aH[i], bL[j], acc[i][j]);
        acc[i][j] = MFMA(aL[i], bH[j], acc[i][j]);
      }
  }

  const int row0 = bm + wm * 64 + g * 4;
  const int col0 = bn + wn * 64 + fr;
  float bj[4];
#pragma unroll
  for (int j = 0; j < 4; ++j) bj[j] = bias[col0 + j * 16];
#pragma unroll
  for (int i = 0; i < 4; ++i)
#pragma unroll
    for (int j = 0; j < 4; ++j) {
      const int row = row0 + i * 16, col = col0 + j * 16;
#pragma unroll
      for (int r = 0; r < 4; ++r)
        Cf[(size_t)(row + r) * Ndim + col] = acc[i][j][r] + bj[j];
    }
}

// ---------------------------------------------------------------------------
// Flash attention (proven round-8 kernel). 256 thr = 4 waves x 32 q-rows,
// KV tiles 64, GLDS-staged K/V (swizzled source), QK 3-term, PV 2-term,
// row-sum via ones-MFMA. LDS 51200 B -> 3 blocks/CU; grid 768.
// ---------------------------------------------------------------------------
__global__ __launch_bounds__(256, 3)
void k_attn(const short* __restrict__ qkH, const short* __restrict__ qkL,
            const short* __restrict__ vTH, const short* __restrict__ vTL,
            short* __restrict__ attH, short* __restrict__ attL)
{
  __shared__ __align__(16) short Kls[2][64 * 64];
  __shared__ __align__(16) short Vls[2][64 * 64];
  __shared__ __align__(16) short Ps[4][32][72];

  const int tid = threadIdx.x, lane = tid & 63, w = tid >> 6;
  const int fr = lane & 15, g = lane >> 4;
  const int l3 = lane >> 3;
  const int ssrc = (lane & 7) ^ l3;

  const int bid = blockIdx.x;
  const int lg = (bid & 7) * 96 + (bid >> 3);
  const int qt = lg & 7;
  const int bh = lg >> 3;
  const int b = bh / 12, h = bh - b * 12;

  const f32x4 zero4 = {0.f, 0.f, 0.f, 0.f};

  short8 qH[2][2], qL[2][2];
#pragma unroll
  for (int i = 0; i < 2; ++i) {
    const int row = qt * 128 + w * 32 + i * 16 + fr;
    const size_t base = (size_t)(b * 1024 + row) * 1536 + h * 128 + g * 8;
#pragma unroll
    for (int ks = 0; ks < 2; ++ks) {
      qH[i][ks] = *(const short8*)&qkH[base + ks * 32];
      qL[i][ks] = *(const short8*)&qkL[base + ks * 32];
    }
  }

  f32x4 O[2][4];
  float mrun[2][4], lrun[2][4];
#pragma unroll
  for (int i = 0; i < 2; ++i)
#pragma unroll
    for (int r = 0; r < 4; ++r) { mrun[i][r] = -INFINITY; lrun[i][r] = 0.f; }
#pragma unroll
  for (int i = 0; i < 2; ++i)
#pragma unroll
    for (int nf = 0; nf < 4; ++nf) O[i][nf] = zero4;

  short8 ones;
#pragma unroll
  for (int e = 0; e < 8; ++e) ones[e] = (short)0x3F80;

  const short* kplane = (w & 1) ? qkL : qkH;
  const short* vplane = (w & 1) ? vTL : vTH;
  short* dstA = (w < 2) ? &Kls[w & 1][0] : &Vls[w & 1][0];

  for (int kt = 0; kt < 16; ++kt) {
    const int kv0 = kt * 64;
    __syncthreads();
#pragma unroll
    for (int c = 0; c < 8; ++c) {
      const int row = c * 8 + l3;
      const short* src = (w < 2)
        ? kplane + (size_t)(b * 1024 + kv0 + row) * 1536 + h * 128 + 64 + ssrc * 8
        : vplane + ((size_t)bh * 64 + row) * 1024 + kv0 + ssrc * 8;
      GLDS16(src, dstA + c * 512);
    }
    __syncthreads();

    f32x4 S[2][4];
#pragma unroll
    for (int i = 0; i < 2; ++i)
#pragma unroll
      for (int nf = 0; nf < 4; ++nf) S[i][nf] = zero4;
#pragma unroll
    for (int nf = 0; nf < 4; ++nf) {
      const int rk = nf * 16 + fr;
#pragma unroll
      for (int ks = 0; ks < 2; ++ks) {
        const int t = g + 4 * ks;
        const int sidx = rk * 64 + ((t ^ (rk & 7)) * 8);
        short8 kbh = *(const short8*)&Kls[0][sidx];
        short8 kbl = *(const short8*)&Kls[1][sidx];
#pragma unroll
        for (int i = 0; i < 2; ++i) {
          S[i][nf] = MFMA(qH[i][ks], kbh, S[i][nf]);
          S[i][nf] = MFMA(qH[i][ks], kbl, S[i][nf]);
          S[i][nf] = MFMA(qL[i][ks], kbh, S[i][nf]);
        }
      }
    }

    float al[2][4];
#pragma unroll
    for (int i = 0; i < 2; ++i) {
      float tl[4];
#pragma unroll
      for (int r = 0; r < 4; ++r)
        tl[r] = fmaxf(fmaxf(S[i][0][r], S[i][1][r]), fmaxf(S[i][2][r], S[i][3][r]));
#pragma unroll
      for (int off = 1; off < 16; off <<= 1)
#pragma unroll
        for (int r = 0; r < 4; ++r) tl[r] = fmaxf(tl[r], __shfl_xor(tl[r], off));
#pragma unroll
      for (int r = 0; r < 4; ++r) {
        const float mn = fmaxf(mrun[i][r], tl[r] * 8.f);
        al[i][r] = __expf(mrun[i][r] - mn);
        mrun[i][r] = mn;
#pragma unroll
        for (int nf = 0; nf < 4; ++nf) {
          const float p = __expf(fmaf(S[i][nf][r], 8.f, -mn));
          Ps[w][i * 16 + g * 4 + r][nf * 16 + fr] = (short)f2bf(p);
        }
      }
    }

    short8 pa[2][2];
#pragma unroll
    for (int i = 0; i < 2; ++i)
#pragma unroll
      for (int ks = 0; ks < 2; ++ks)
        pa[i][ks] = *(const short8*)&Ps[w][i * 16 + fr][ks * 32 + g * 8];

#pragma unroll
    for (int i = 0; i < 2; ++i) {
      f32x4 rs = MFMA(pa[i][0], ones, zero4);
      rs = MFMA(pa[i][1], ones, rs);
#pragma unroll
      for (int r = 0; r < 4; ++r)
        lrun[i][r] = lrun[i][r] * al[i][r] + rs[r];
#pragma unroll
      for (int nf = 0; nf < 4; ++nf)
#pragma unroll
        for (int r = 0; r < 4; ++r) O[i][nf][r] *= al[i][r];
    }

#pragma unroll
    for (int nf = 0; nf < 4; ++nf) {
      const int rd = nf * 16 + fr;
#pragma unroll
      for (int ks = 0; ks < 2; ++ks) {
        const int t = g + 4 * ks;
        const int sidx = rd * 64 + ((t ^ (rd & 7)) * 8);
        short8 vbh = *(const short8*)&Vls[0][sidx];
        short8 vbl = *(const short8*)&Vls[1][sidx];
#pragma unroll
        for (int i = 0; i < 2; ++i) {
          O[i][nf] = MFMA(pa[i][ks], vbh, O[i][nf]);
          O[i][nf] = MFMA(pa[i][ks], vbl, O[i][nf]);
        }
      }
    }
  }

#pragma unroll
  for (int i = 0; i < 2; ++i) {
    const size_t rowbase = (size_t)(b * 1024 + qt * 128 + w * 32 + i * 16 + g * 4);
#pragma unroll
    for (int r = 0; r < 4; ++r) {
      const float inv = 1.f / lrun[i][r];
#pragma unroll
      for (int nf = 0; nf < 4; ++nf) {
        const float v = O[i][nf][r] * inv;
        const size_t idx = (rowbase + r) * 768 + h * 64 + nf * 16 + fr;
        const unsigned short hi = f2bf(v);
        attH[idx] = (short)hi;
        attL[idx] = (short)f2bf(v - bf2f(hi));
      }
    }
  }
}

// ---------------------------------------------------------------------------

extern "C" void kernel_launch(void* const* d_in, const int* in_sizes, int n_in,
                              void* d_out, int out_size, void* d_ws, size_t ws_size,
                              hipStream_t stream)
{
  const float* img  = (const float*)d_in[0];   // [8,1024,768]
  const float* Wqkv = (const float*)d_in[1];   // [2304,768]
  const float* Wfc  = (const float*)d_in[2];   // [768,768]
  const float* bfc  = (const float*)d_in[3];   // [768]
  float* outp = (float*)d_out;                 // [8,1024,768] fp32

  char* ws = (char*)d_ws;
  short* qkH   = (short*)(ws);                  //  0       (25.2 MB)
  short* qkL   = (short*)(ws + 25165824);
  short* vTH   = (short*)(ws + 50331648);       // 12.6 MB
  short* vTL   = (short*)(ws + 62914560);
  short* imgH  = (short*)(ws + 75497472);       // 12.6 MB (aliased attH)
  short* imgL  = (short*)(ws + 88080384);       // 12.6 MB (aliased attL)
  short* WqkvH = (short*)(ws + 100663296);
  short* WqkvL = (short*)(ws + 104202240);
  short* WfcH  = (short*)(ws + 107741184);
  short* WfcL  = (short*)(ws + 108920832);      // end 110,100,480
  short* attH  = imgH;
  short* attL  = imgL;

  // 0) fp32 -> planar hi/lo bf16
  k_split<<<3072, 256, 0, stream>>>(img,  imgH,  imgL,  786432);
  k_split<<<864,  256, 0, stream>>>(Wqkv, WqkvH, WqkvL, 221184);
  k_split<<<288,  256, 0, stream>>>(Wfc,  WfcH,  WfcL,  73728);
  // 1) qkv = img @ Wqkv^T  -> qk planar + vT planar  (8-phase pipeline)
  k_gemm8<<<dim3(64, 12), dim3(384), 0, stream>>>(
      imgH, imgL, WqkvH, WqkvL, qkH, qkL, vTH, vTL);
  // 2) flash attention -> att planar
  k_attn<<<dim3(768), dim3(256), 0, stream>>>(qkH, qkL, vTH, vTL, attH, attL);
  // 3) out = att @ Wfc^T + b  (fp32)
  k_gemm<<<dim3(64, 6), dim3(256), 0, stream>>>(
      attH, attL, WfcH, WfcL, bfc, outp, 768, 768);
}

// Round 10
// 298.535 us; speedup vs baseline: 1.0485x; 1.0485x over previous
//
#include <hip/hip_runtime.h>
#include <math.h>

// B=8, N=1024, DIM=768, H=12, dh=64 -> M=8192, EQKV=2304
// Split-precision bf16: x ~= hi + lo. 3-term MFMA GEMMs, 3-term QK, 2-term PV.
// GEMMs: 128x128 tile, BK=32, 4 waves, DOUBLE-BUFFERED issue-early staging
// (stage next tile -> compute current -> one __syncthreads per tile).
// All staging via global_load_lds with XOR-swizzled sources (T2/m173).

typedef __attribute__((ext_vector_type(8))) short short8;
typedef __attribute__((ext_vector_type(4))) float f32x4;

#define MFMA(a, b, c) __builtin_amdgcn_mfma_f32_16x16x32_bf16((a), (b), (c), 0, 0, 0)

#define GLDS16(gp, lp) \
  __builtin_amdgcn_global_load_lds((__attribute__((address_space(1))) const void*)(gp), \
                                   (__attribute__((address_space(3))) void*)(lp), 16, 0, 0)

__device__ __forceinline__ unsigned short f2bf(float x) {
  unsigned u = __builtin_bit_cast(unsigned, x);
  return (unsigned short)((u + 0x7FFFu + ((u >> 16) & 1u)) >> 16);
}
__device__ __forceinline__ float bf2f(unsigned short h) {
  unsigned u = ((unsigned)h) << 16;
  return __builtin_bit_cast(float, u);
}

// ---------------------------------------------------------------------------
// fp32 -> planar (hi, lo) bf16 split, 8 elem/thread.
// ---------------------------------------------------------------------------
__global__ __launch_bounds__(256)
void k_split(const float* __restrict__ x, short* __restrict__ h,
             short* __restrict__ l, int n8)
{
  const int i = blockIdx.x * 256 + threadIdx.x;
  if (i >= n8) return;
  float4 a = ((const float4*)x)[2 * i];
  float4 b = ((const float4*)x)[2 * i + 1];
  float v[8] = {a.x, a.y, a.z, a.w, b.x, b.y, b.z, b.w};
  short8 hh, ll;
#pragma unroll
  for (int e = 0; e < 8; ++e) {
    unsigned short hi = f2bf(v[e]);
    hh[e] = (short)hi;
    ll[e] = (short)f2bf(v[e] - bf2f(hi));
  }
  ((short8*)h)[i] = hh;
  ((short8*)l)[i] = ll;
}

// ---------------------------------------------------------------------------
// C[M x Ndim] = (AH+AL) * (WH+WL)^T, 3-term. 128x128 tile, BK=32, 256 thr.
// Double-buffered LDS; per tile: stage(next) -> ds_read(cur) -> MFMA -> sync.
// LDS rows: 64 shorts = [32 H | 32 L], XOR-swizzled in 16B slots.
// EPI=0: route qkv -> qk planar [8192][1536] + vT planar [96][64][1024].
// EPI=1: fp32 + bias.
// ---------------------------------------------------------------------------
template <int EPI>
__global__ __launch_bounds__(256, 2)
void k_gemm(const short* __restrict__ AH, const short* __restrict__ AL,
            const short* __restrict__ WH, const short* __restrict__ WL,
            const float* __restrict__ bias, float* __restrict__ Cf,
            short* __restrict__ qkH, short* __restrict__ qkL,
            short* __restrict__ vTH, short* __restrict__ vTL,
            int Ndim, int K)
{
  __shared__ __align__(16) short As[2][128 * 64];   // 2 x 16 KiB
  __shared__ __align__(16) short Ws[2][128 * 64];   // 2 x 16 KiB

  const int tid = threadIdx.x, lane = tid & 63, w = tid >> 6;
  const int wm = w >> 1, wn = w & 1;
  const int fr = lane & 15, g = lane >> 4;
  const int bm = blockIdx.x * 128, bn = blockIdx.y * 128;

  const int l3 = lane >> 3;            // 0..7
  const int ssrc = (lane & 7) ^ l3;    // source slot for linear-dest swizzle

  const f32x4 zero4 = {0.f, 0.f, 0.f, 0.f};
  f32x4 acc[4][4];
#pragma unroll
  for (int i = 0; i < 4; ++i)
#pragma unroll
    for (int j = 0; j < 4; ++j) acc[i][j] = zero4;

  const short* aplane = (ssrc < 4) ? AH : AL;
  const short* wplane = (ssrc < 4) ? WH : WL;
  const int scol = (ssrc & 3) * 8;

  // stage a full 32-K-slab of A+W into buffer `buf` (8 x 1KiB chunks/wave)
  auto stage = [&](int buf, int kt) {
    const int k0 = kt << 5;
#pragma unroll
    for (int c = 0; c < 8; ++c) {
      const int gidx = w * 8 + c;
      const int ch = gidx & 15;
      const int row = ch * 8 + l3;
      if (gidx < 16) {
        GLDS16(aplane + (size_t)(bm + row) * K + k0 + scol, &As[buf][ch * 512]);
      } else {
        GLDS16(wplane + (size_t)(bn + row) * K + k0 + scol, &Ws[buf][ch * 512]);
      }
    }
  };

  const int nk = K >> 5;
  stage(0, 0);
  __syncthreads();                     // buffer 0 ready

  int cur = 0;
  for (int kt = 0; kt < nk; ++kt) {
    if (kt + 1 < nk) stage(cur ^ 1, kt + 1);   // issue-early, no wait

    short8 aH[4], aL[4], bH[4], bL[4];
#pragma unroll
    for (int i = 0; i < 4; ++i) {
      const int ra = wm * 64 + i * 16 + fr;
      aH[i] = *(const short8*)&As[cur][ra * 64 + ((g ^ (ra & 7)) * 8)];
      aL[i] = *(const short8*)&As[cur][ra * 64 + (((4 + g) ^ (ra & 7)) * 8)];
      const int rb = wn * 64 + i * 16 + fr;
      bH[i] = *(const short8*)&Ws[cur][rb * 64 + ((g ^ (rb & 7)) * 8)];
      bL[i] = *(const short8*)&Ws[cur][rb * 64 + (((4 + g) ^ (rb & 7)) * 8)];
    }
    __builtin_amdgcn_s_setprio(1);
#pragma unroll
    for (int i = 0; i < 4; ++i)
#pragma unroll
      for (int j = 0; j < 4; ++j) {
        acc[i][j] = MFMA(aH[i], bH[j], acc[i][j]);
        acc[i][j] = MFMA(aH[i], bL[j], acc[i][j]);
        acc[i][j] = MFMA(aL[i], bH[j], acc[i][j]);
      }
    __builtin_amdgcn_s_setprio(0);
    __syncthreads();                   // drain-late: stage had full compute to land
    cur ^= 1;
  }

  // ---- epilogue (D-layout: col=lane&15, row=(lane>>4)*4+r) ----
  const int row0 = bm + wm * 64 + g * 4;
  if constexpr (EPI == 0) {
    const int colbase = bn + wn * 64;           // 64-aligned, single species
    const int species = (colbase >> 6) % 3;     // 0:q 1:k 2:v
    const int head = colbase / 192;
    if (species < 2) {
      const int qkcol0 = head * 128 + species * 64 + fr;
#pragma unroll
      for (int i = 0; i < 4; ++i)
#pragma unroll
        for (int j = 0; j < 4; ++j) {
          const size_t base = (size_t)(row0 + i * 16) * 1536 + qkcol0 + j * 16;
#pragma unroll
          for (int r = 0; r < 4; ++r) {
            const float x = acc[i][j][r];
            const unsigned short hi = f2bf(x);
            qkH[base + (size_t)r * 1536] = (short)hi;
            qkL[base + (size_t)r * 1536] = (short)f2bf(x - bf2f(hi));
          }
        }
    } else {
#pragma unroll
      for (int i = 0; i < 4; ++i) {
        const int n0 = row0 + i * 16;
        const int b = n0 >> 10, n = n0 & 1023;
#pragma unroll
        for (int j = 0; j < 4; ++j) {
          const int dv = j * 16 + fr;
          short4 h4, l4;
#pragma unroll
          for (int r = 0; r < 4; ++r) {
            const float x = acc[i][j][r];
            const unsigned short hi = f2bf(x);
            ((short*)&h4)[r] = (short)hi;
            ((short*)&l4)[r] = (short)f2bf(x - bf2f(hi));
          }
          const size_t vidx = ((size_t)(b * 12 + head) * 64 + dv) * 1024 + n;
          *(short4*)&vTH[vidx] = h4;
          *(short4*)&vTL[vidx] = l4;
        }
      }
    }
  } else {
    const int col0 = bn + wn * 64 + fr;
    float bj[4];
#pragma unroll
    for (int j = 0; j < 4; ++j) bj[j] = bias[col0 + j * 16];
#pragma unroll
    for (int i = 0; i < 4; ++i)
#pragma unroll
      for (int j = 0; j < 4; ++j) {
        const int row = row0 + i * 16, col = col0 + j * 16;
#pragma unroll
        for (int r = 0; r < 4; ++r)
          Cf[(size_t)(row + r) * Ndim + col] = acc[i][j][r] + bj[j];
      }
  }
}

// ---------------------------------------------------------------------------
// Flash attention (proven round-8 kernel, unchanged). 256 thr = 4 waves x
// 32 q-rows, KV tiles 64, GLDS-staged K/V (swizzled source), QK 3-term,
// PV 2-term, row-sum via ones-MFMA. LDS 51200 B -> 3 blocks/CU; grid 768.
// ---------------------------------------------------------------------------
__global__ __launch_bounds__(256, 3)
void k_attn(const short* __restrict__ qkH, const short* __restrict__ qkL,
            const short* __restrict__ vTH, const short* __restrict__ vTL,
            short* __restrict__ attH, short* __restrict__ attL)
{
  __shared__ __align__(16) short Kls[2][64 * 64];
  __shared__ __align__(16) short Vls[2][64 * 64];
  __shared__ __align__(16) short Ps[4][32][72];

  const int tid = threadIdx.x, lane = tid & 63, w = tid >> 6;
  const int fr = lane & 15, g = lane >> 4;
  const int l3 = lane >> 3;
  const int ssrc = (lane & 7) ^ l3;

  const int bid = blockIdx.x;
  const int lg = (bid & 7) * 96 + (bid >> 3);
  const int qt = lg & 7;
  const int bh = lg >> 3;
  const int b = bh / 12, h = bh - b * 12;

  const f32x4 zero4 = {0.f, 0.f, 0.f, 0.f};

  short8 qH[2][2], qL[2][2];
#pragma unroll
  for (int i = 0; i < 2; ++i) {
    const int row = qt * 128 + w * 32 + i * 16 + fr;
    const size_t base = (size_t)(b * 1024 + row) * 1536 + h * 128 + g * 8;
#pragma unroll
    for (int ks = 0; ks < 2; ++ks) {
      qH[i][ks] = *(const short8*)&qkH[base + ks * 32];
      qL[i][ks] = *(const short8*)&qkL[base + ks * 32];
    }
  }

  f32x4 O[2][4];
  float mrun[2][4], lrun[2][4];
#pragma unroll
  for (int i = 0; i < 2; ++i)
#pragma unroll
    for (int r = 0; r < 4; ++r) { mrun[i][r] = -INFINITY; lrun[i][r] = 0.f; }
#pragma unroll
  for (int i = 0; i < 2; ++i)
#pragma unroll
    for (int nf = 0; nf < 4; ++nf) O[i][nf] = zero4;

  short8 ones;
#pragma unroll
  for (int e = 0; e < 8; ++e) ones[e] = (short)0x3F80;

  const short* kplane = (w & 1) ? qkL : qkH;
  const short* vplane = (w & 1) ? vTL : vTH;
  short* dstA = (w < 2) ? &Kls[w & 1][0] : &Vls[w & 1][0];

  for (int kt = 0; kt < 16; ++kt) {
    const int kv0 = kt * 64;
    __syncthreads();
#pragma unroll
    for (int c = 0; c < 8; ++c) {
      const int row = c * 8 + l3;
      const short* src = (w < 2)
        ? kplane + (size_t)(b * 1024 + kv0 + row) * 1536 + h * 128 + 64 + ssrc * 8
        : vplane + ((size_t)bh * 64 + row) * 1024 + kv0 + ssrc * 8;
      GLDS16(src, dstA + c * 512);
    }
    __syncthreads();

    f32x4 S[2][4];
#pragma unroll
    for (int i = 0; i < 2; ++i)
#pragma unroll
      for (int nf = 0; nf < 4; ++nf) S[i][nf] = zero4;
#pragma unroll
    for (int nf = 0; nf < 4; ++nf) {
      const int rk = nf * 16 + fr;
#pragma unroll
      for (int ks = 0; ks < 2; ++ks) {
        const int t = g + 4 * ks;
        const int sidx = rk * 64 + ((t ^ (rk & 7)) * 8);
        short8 kbh = *(const short8*)&Kls[0][sidx];
        short8 kbl = *(const short8*)&Kls[1][sidx];
#pragma unroll
        for (int i = 0; i < 2; ++i) {
          S[i][nf] = MFMA(qH[i][ks], kbh, S[i][nf]);
          S[i][nf] = MFMA(qH[i][ks], kbl, S[i][nf]);
          S[i][nf] = MFMA(qL[i][ks], kbh, S[i][nf]);
        }
      }
    }

    float al[2][4];
#pragma unroll
    for (int i = 0; i < 2; ++i) {
      float tl[4];
#pragma unroll
      for (int r = 0; r < 4; ++r)
        tl[r] = fmaxf(fmaxf(S[i][0][r], S[i][1][r]), fmaxf(S[i][2][r], S[i][3][r]));
#pragma unroll
      for (int off = 1; off < 16; off <<= 1)
#pragma unroll
        for (int r = 0; r < 4; ++r) tl[r] = fmaxf(tl[r], __shfl_xor(tl[r], off));
#pragma unroll
      for (int r = 0; r < 4; ++r) {
        const float mn = fmaxf(mrun[i][r], tl[r] * 8.f);
        al[i][r] = __expf(mrun[i][r] - mn);
        mrun[i][r] = mn;
#pragma unroll
        for (int nf = 0; nf < 4; ++nf) {
          const float p = __expf(fmaf(S[i][nf][r], 8.f, -mn));
          Ps[w][i * 16 + g * 4 + r][nf * 16 + fr] = (short)f2bf(p);
        }
      }
    }

    short8 pa[2][2];
#pragma unroll
    for (int i = 0; i < 2; ++i)
#pragma unroll
      for (int ks = 0; ks < 2; ++ks)
        pa[i][ks] = *(const short8*)&Ps[w][i * 16 + fr][ks * 32 + g * 8];

#pragma unroll
    for (int i = 0; i < 2; ++i) {
      f32x4 rs = MFMA(pa[i][0], ones, zero4);
      rs = MFMA(pa[i][1], ones, rs);
#pragma unroll
      for (int r = 0; r < 4; ++r)
        lrun[i][r] = lrun[i][r] * al[i][r] + rs[r];
#pragma unroll
      for (int nf = 0; nf < 4; ++nf)
#pragma unroll
        for (int r = 0; r < 4; ++r) O[i][nf][r] *= al[i][r];
    }

#pragma unroll
    for (int nf = 0; nf < 4; ++nf) {
      const int rd = nf * 16 + fr;
#pragma unroll
      for (int ks = 0; ks < 2; ++ks) {
        const int t = g + 4 * ks;
        const int sidx = rd * 64 + ((t ^ (rd & 7)) * 8);
        short8 vbh = *(const short8*)&Vls[0][sidx];
        short8 vbl = *(const short8*)&Vls[1][sidx];
#pragma unroll
        for (int i = 0; i < 2; ++i) {
          O[i][nf] = MFMA(pa[i][ks], vbh, O[i][nf]);
          O[i][nf] = MFMA(pa[i][ks], vbl, O[i][nf]);
        }
      }
    }
  }

#pragma unroll
  for (int i = 0; i < 2; ++i) {
    const size_t rowbase = (size_t)(b * 1024 + qt * 128 + w * 32 + i * 16 + g * 4);
#pragma unroll
    for (int r = 0; r < 4; ++r) {
      const float inv = 1.f / lrun[i][r];
#pragma unroll
      for (int nf = 0; nf < 4; ++nf) {
        const float v = O[i][nf][r] * inv;
        const size_t idx = (rowbase + r) * 768 + h * 64 + nf * 16 + fr;
        const unsigned short hi = f2bf(v);
        attH[idx] = (short)hi;
        attL[idx] = (short)f2bf(v - bf2f(hi));
      }
    }
  }
}

// ---------------------------------------------------------------------------

extern "C" void kernel_launch(void* const* d_in, const int* in_sizes, int n_in,
                              void* d_out, int out_size, void* d_ws, size_t ws_size,
                              hipStream_t stream)
{
  const float* img  = (const float*)d_in[0];   // [8,1024,768]
  const float* Wqkv = (const float*)d_in[1];   // [2304,768]
  const float* Wfc  = (const float*)d_in[2];   // [768,768]
  const float* bfc  = (const float*)d_in[3];   // [768]
  float* outp = (float*)d_out;                 // [8,1024,768] fp32

  char* ws = (char*)d_ws;
  short* qkH   = (short*)(ws);                  //  0       (25.2 MB)
  short* qkL   = (short*)(ws + 25165824);
  short* vTH   = (short*)(ws + 50331648);       // 12.6 MB
  short* vTL   = (short*)(ws + 62914560);
  short* imgH  = (short*)(ws + 75497472);       // 12.6 MB (aliased attH)
  short* imgL  = (short*)(ws + 88080384);       // 12.6 MB (aliased attL)
  short* WqkvH = (short*)(ws + 100663296);
  short* WqkvL = (short*)(ws + 104202240);
  short* WfcH  = (short*)(ws + 107741184);
  short* WfcL  = (short*)(ws + 108920832);      // end 110,100,480
  short* attH  = imgH;
  short* attL  = imgL;

  // 0) fp32 -> planar hi/lo bf16
  k_split<<<3072, 256, 0, stream>>>(img,  imgH,  imgL,  786432);
  k_split<<<864,  256, 0, stream>>>(Wqkv, WqkvH, WqkvL, 221184);
  k_split<<<288,  256, 0, stream>>>(Wfc,  WfcH,  WfcL,  73728);
  // 1) qkv = img @ Wqkv^T  -> qk planar + vT planar  (dbuf issue-early)
  k_gemm<0><<<dim3(64, 18), dim3(256), 0, stream>>>(
      imgH, imgL, WqkvH, WqkvL, nullptr, nullptr,
      qkH, qkL, vTH, vTL, 2304, 768);
  // 2) flash attention -> att planar
  k_attn<<<dim3(768), dim3(256), 0, stream>>>(qkH, qkL, vTH, vTL, attH, attL);
  // 3) out = att @ Wfc^T + b  (fp32, dbuf issue-early)
  k_gemm<1><<<dim3(64, 6), dim3(256), 0, stream>>>(
      attH, attL, WfcH, WfcL, bfc, outp,
      nullptr, nullptr, nullptr, nullptr, 768, 768);
}